// Round 10
// baseline (203.499 us; speedup 1.0000x reference)
//
#include <hip/hip_runtime.h>
#include <hip/hip_bf16.h>
#include <cstdint>

#define CH 2048
#define NCF 8192          // 4 * CH
#define NJ 24             // 4 pre + 4 post + 16 res
#define RPB 4             // batch rows per block
#define EPS_F 1e-5f
#define SINK_ITERS 20

typedef float v4f __attribute__((ext_vector_type(4)));

__device__ __forceinline__ uint32_t bf16rne(float f) {
    uint32_t u = __float_as_uint(f);
    return (u + 0x7fffu + ((u >> 16) & 1u)) >> 16;
}

// dot of 8 bf16 pairs (packed in uint4) via v_dot2_f32_bf16
__device__ __forceinline__ float dot8(const uint4& x, const uint4& p, float acc) {
    asm("v_dot2_f32_bf16 %0, %1, %2, %0" : "+v"(acc) : "v"(x.x), "v"(p.x));
    asm("v_dot2_f32_bf16 %0, %1, %2, %0" : "+v"(acc) : "v"(x.y), "v"(p.y));
    asm("v_dot2_f32_bf16 %0, %1, %2, %0" : "+v"(acc) : "v"(x.z), "v"(p.z));
    asm("v_dot2_f32_bf16 %0, %1, %2, %0" : "+v"(acc) : "v"(x.w), "v"(p.w));
    return acc;
}

// ---------------------------------------------------------------------------
// Prep: phiW[j][k] = bf16( alpha_j * w[k % CH] * phi_j[k] ),  j in [0,24)
// ---------------------------------------------------------------------------
__global__ void __launch_bounds__(256) prep_phi_kernel(
    const float* __restrict__ w,
    const float* __restrict__ phi_pre,
    const float* __restrict__ phi_post,
    const float* __restrict__ phi_res,
    const float* __restrict__ alpha_pre,
    const float* __restrict__ alpha_post,
    const float* __restrict__ alpha_res,
    uint16_t* __restrict__ phiW)
{
    int idx = blockIdx.x * 256 + threadIdx.x;
    if (idx >= NJ * NCF) return;
    int j = idx / NCF;
    int k = idx - j * NCF;
    int c = k & (CH - 1);
    float v, a;
    if (j < 4)      { v = phi_pre[j * NCF + k];        a = alpha_pre[0]; }
    else if (j < 8) { v = phi_post[(j - 4) * NCF + k]; a = alpha_post[0]; }
    else            { v = phi_res[(j - 8) * NCF + k];  a = alpha_res[0]; }
    phiW[idx] = (uint16_t)bf16rne(v * a * w[c]);
}

// ---------------------------------------------------------------------------
// Main fused kernel: 1024 threads (16 waves), FOUR batch rows per block.
// LDS holds raw bf16 x for 4 rows (64 KiB) -> 2 blocks/CU, 32 waves/CU.
// Phase B: wave w owns j-triple (w>>1) and k-half (w&1): 8 ping-pong steps.
// RMS scale folded at stream-segment boundaries. Wave-pair partials combine
// via LDS. Sinkhorn: 16-lane groups, all waves redundant. 3 barriers.
// ---------------------------------------------------------------------------
__global__ void __launch_bounds__(1024, 2) mhc_main_kernel(
    const float* __restrict__ x,
    const uint16_t* __restrict__ phiW,
    const float* __restrict__ b_pre,
    const float* __restrict__ b_post,
    const float* __restrict__ b_res,
    float* __restrict__ out)
{
    const int t = threadIdx.x;
    const int lane = t & 63;
    const int wave = t >> 6;              // 0..15
    const long b0 = (long)blockIdx.x * RPB;

    __shared__ uint32_t xn[RPB][NCF / 2]; // raw bf16 x, 4 rows, 64 KiB
    __shared__ float redA[RPB][16];       // f1 (streams 0/1) partials
    __shared__ float redB[RPB][16];       // f2 (streams 2/3) partials
    __shared__ float hredp[16][12];       // per-wave dot partials
    __shared__ float H[RPB][24];

    // ---- Phase A: global -> LDS (raw bf16), sum-of-squares ----
    // thread t loads float4 idx t (stream t>>9) and t+1024 (stream 2+(t>>9))
    {
        const float4* xp = reinterpret_cast<const float4*>(x + b0 * NCF);
        float ssA[RPB], ssB[RPB];
        #pragma unroll
        for (int r = 0; r < RPB; ++r) {
            float4 a = xp[r * 2048 + t];
            float4 b = xp[r * 2048 + t + 1024];
            ssA[r] = a.x*a.x + a.y*a.y + a.z*a.z + a.w*a.w;
            ssB[r] = b.x*b.x + b.y*b.y + b.z*b.z + b.w*b.w;
            *reinterpret_cast<uint2*>(&xn[r][2 * t]) =
                make_uint2(bf16rne(a.x) | (bf16rne(a.y) << 16),
                           bf16rne(a.z) | (bf16rne(a.w) << 16));
            *reinterpret_cast<uint2*>(&xn[r][2 * t + 2048]) =
                make_uint2(bf16rne(b.x) | (bf16rne(b.y) << 16),
                           bf16rne(b.z) | (bf16rne(b.w) << 16));
        }
        #pragma unroll
        for (int m = 1; m < 64; m <<= 1) {
            #pragma unroll
            for (int r = 0; r < RPB; ++r) {
                ssA[r] += __shfl_xor(ssA[r], m, 64);
                ssB[r] += __shfl_xor(ssB[r], m, 64);
            }
        }
        if (lane == 0) {
            #pragma unroll
            for (int r = 0; r < RPB; ++r) {
                redA[r][wave] = ssA[r];
                redB[r][wave] = ssB[r];
            }
        }
    }
    __syncthreads();

    // ---- SCL computed redundantly per thread (vector broadcast reads) ----
    // waves 0-7 f1 -> stream0, waves 8-15 f1 -> stream1,
    // waves 0-7 f2 -> stream2, waves 8-15 f2 -> stream3
    float scl[RPB][4];
    #pragma unroll
    for (int r = 0; r < RPB; ++r) {
        const float4* ra = reinterpret_cast<const float4*>(redA[r]);
        const float4* rb = reinterpret_cast<const float4*>(redB[r]);
        float4 a0 = ra[0], a1 = ra[1], a2 = ra[2], a3 = ra[3];
        float4 c0 = rb[0], c1 = rb[1], c2 = rb[2], c3 = rb[3];
        float s0 = a0.x+a0.y+a0.z+a0.w + a1.x+a1.y+a1.z+a1.w;
        float s1 = a2.x+a2.y+a2.z+a2.w + a3.x+a3.y+a3.z+a3.w;
        float s2 = c0.x+c0.y+c0.z+c0.w + c1.x+c1.y+c1.z+c1.w;
        float s3 = c2.x+c2.y+c2.z+c2.w + c3.x+c3.y+c3.z+c3.w;
        scl[r][0] = rsqrtf(s0 * (1.0f / CH) + EPS_F);
        scl[r][1] = rsqrtf(s1 * (1.0f / CH) + EPS_F);
        scl[r][2] = rsqrtf(s2 * (1.0f / CH) + EPS_F);
        scl[r][3] = rsqrtf(s3 * (1.0f / CH) + EPS_F);
    }

    // ---- Phase B: wave w = 2*jt + h dots k-half h against phi triple jt --
    float accT[3][RPB] = {};
    float accS[3][RPB] = {};
    {
        const int jt = wave >> 1;
        const int h  = wave & 1;
        const int u0 = 8 * h;
        const uint16_t* pw = phiW + (size_t)(jt * 3) * NCF;
        const int kl = 8 * lane;
        const uint4* xr0 = reinterpret_cast<const uint4*>(xn[0]);
        const uint4* xr1 = reinterpret_cast<const uint4*>(xn[1]);
        const uint4* xr2 = reinterpret_cast<const uint4*>(xn[2]);
        const uint4* xr3 = reinterpret_cast<const uint4*>(xn[3]);

        const int kF = 512 * u0 + kl;
        const int iF = 64 * u0 + lane;
        uint4 pA0 = *reinterpret_cast<const uint4*>(pw + 0 * NCF + kF);
        uint4 pA1 = *reinterpret_cast<const uint4*>(pw + 1 * NCF + kF);
        uint4 pA2 = *reinterpret_cast<const uint4*>(pw + 2 * NCF + kF);
        uint4 xA0 = xr0[iF], xA1 = xr1[iF], xA2 = xr2[iF], xA3 = xr3[iF];

        #pragma unroll
        for (int du = 0; du < 8; du += 2) {
            const int u = u0 + du;
            const int iB = 64 * (u + 1) + lane;
            const int kB = 512 * (u + 1) + kl;
            uint4 pB0 = *reinterpret_cast<const uint4*>(pw + 0 * NCF + kB);
            uint4 pB1 = *reinterpret_cast<const uint4*>(pw + 1 * NCF + kB);
            uint4 pB2 = *reinterpret_cast<const uint4*>(pw + 2 * NCF + kB);
            uint4 xB0 = xr0[iB], xB1 = xr1[iB], xB2 = xr2[iB], xB3 = xr3[iB];

            accS[0][0] = dot8(xA0, pA0, accS[0][0]);
            accS[0][1] = dot8(xA1, pA0, accS[0][1]);
            accS[0][2] = dot8(xA2, pA0, accS[0][2]);
            accS[0][3] = dot8(xA3, pA0, accS[0][3]);
            accS[1][0] = dot8(xA0, pA1, accS[1][0]);
            accS[1][1] = dot8(xA1, pA1, accS[1][1]);
            accS[1][2] = dot8(xA2, pA1, accS[1][2]);
            accS[1][3] = dot8(xA3, pA1, accS[1][3]);
            accS[2][0] = dot8(xA0, pA2, accS[2][0]);
            accS[2][1] = dot8(xA1, pA2, accS[2][1]);
            accS[2][2] = dot8(xA2, pA2, accS[2][2]);
            accS[2][3] = dot8(xA3, pA2, accS[2][3]);

            if (du + 2 < 8) {
                const int iA = 64 * (u + 2) + lane;
                const int kA = 512 * (u + 2) + kl;
                pA0 = *reinterpret_cast<const uint4*>(pw + 0 * NCF + kA);
                pA1 = *reinterpret_cast<const uint4*>(pw + 1 * NCF + kA);
                pA2 = *reinterpret_cast<const uint4*>(pw + 2 * NCF + kA);
                xA0 = xr0[iA]; xA1 = xr1[iA]; xA2 = xr2[iA]; xA3 = xr3[iA];
            }

            accS[0][0] = dot8(xB0, pB0, accS[0][0]);
            accS[0][1] = dot8(xB1, pB0, accS[0][1]);
            accS[0][2] = dot8(xB2, pB0, accS[0][2]);
            accS[0][3] = dot8(xB3, pB0, accS[0][3]);
            accS[1][0] = dot8(xB0, pB1, accS[1][0]);
            accS[1][1] = dot8(xB1, pB1, accS[1][1]);
            accS[1][2] = dot8(xB2, pB1, accS[1][2]);
            accS[1][3] = dot8(xB3, pB1, accS[1][3]);
            accS[2][0] = dot8(xB0, pB2, accS[2][0]);
            accS[2][1] = dot8(xB1, pB2, accS[2][1]);
            accS[2][2] = dot8(xB2, pB2, accS[2][2]);
            accS[2][3] = dot8(xB3, pB2, accS[2][3]);

            if (((u + 1) & 3) == 3) {               // end of stream segment
                const int s = (u + 1) >> 2;
                #pragma unroll
                for (int jl = 0; jl < 3; ++jl) {
                    #pragma unroll
                    for (int r = 0; r < RPB; ++r) {
                        accT[jl][r] = fmaf(scl[r][s], accS[jl][r], accT[jl][r]);
                        accS[jl][r] = 0.f;
                    }
                }
            }
        }
    }
    {
        #pragma unroll
        for (int m = 1; m < 64; m <<= 1) {
            #pragma unroll
            for (int jl = 0; jl < 3; ++jl) {
                #pragma unroll
                for (int r = 0; r < RPB; ++r)
                    accT[jl][r] += __shfl_xor(accT[jl][r], m, 64);
            }
        }
        if (lane == 0) {
            #pragma unroll
            for (int jl = 0; jl < 3; ++jl)
                #pragma unroll
                for (int r = 0; r < RPB; ++r)
                    hredp[wave][jl * 4 + r] = accT[jl][r];
        }
    }
    __syncthreads();

    // ---- combine wave-pair partials, fold bias, write H ----
    if (t < 96) {
        const int j = t >> 2;             // 0..23
        const int r = t & 3;
        const int jt2 = j / 3, jl2 = j % 3;
        float v = hredp[2 * jt2][jl2 * 4 + r] + hredp[2 * jt2 + 1][jl2 * 4 + r];
        float bias;
        if (j < 4)      bias = b_pre[j];
        else if (j < 8) bias = b_post[j - 4];
        else            bias = b_res[j - 8];
        H[r][j] = v + bias;
    }
    __syncthreads();

    // ---- Sinkhorn: 16-lane group g handles row g (all waves redundant) ----
    float msink;
    {
        const int r = lane >> 4;
        const int q = lane & 15;          // q = i*4 + jx
        float L = H[r][8 + q];
        float mx = L;
        mx = fmaxf(mx, __shfl_xor(mx, 1, 64));
        mx = fmaxf(mx, __shfl_xor(mx, 2, 64));
        mx = fmaxf(mx, __shfl_xor(mx, 4, 64));
        mx = fmaxf(mx, __shfl_xor(mx, 8, 64));
        float m = __expf(L - mx);
        #pragma unroll
        for (int it = 0; it < SINK_ITERS; ++it) {
            float rs = m + __shfl_xor(m, 1, 64);
            rs += __shfl_xor(rs, 2, 64);
            m = m * __builtin_amdgcn_rcpf(rs + EPS_F);   // row normalize
            float cs = m + __shfl_xor(m, 4, 64);
            cs += __shfl_xor(cs, 8, 64);
            m = m * __builtin_amdgcn_rcpf(cs + EPS_F);   // col normalize
        }
        msink = m;
    }

    // ---- Phase D: mixing epilogue from LDS raw bf16 x ----
    // thread t = hi*512 + q handles rows {2hi, 2hi+1} at channel quad q
    {
        const int hi = t >> 9;
        const int q  = t & 511;
        #pragma unroll
        for (int rr = 0; rr < 2; ++rr) {
            const int r = 2 * hi + rr;
            float hp[4], hq[4], hrm[4][4];
            #pragma unroll
            for (int i = 0; i < 4; ++i) {
                hp[i] = H[r][i];
                hq[i] = H[r][4 + i];
                #pragma unroll
                for (int j = 0; j < 4; ++j)
                    hrm[i][j] = __shfl(msink, 16 * r + 4 * i + j, 64);
            }
            float4 s[4];
            #pragma unroll
            for (int jj = 0; jj < 4; ++jj) {
                uint2 pk = *reinterpret_cast<const uint2*>(&xn[r][2 * q + 1024 * jj]);
                s[jj].x = __uint_as_float(pk.x << 16);
                s[jj].y = __uint_as_float(pk.x & 0xffff0000u);
                s[jj].z = __uint_as_float(pk.y << 16);
                s[jj].w = __uint_as_float(pk.y & 0xffff0000u);
            }
            float ax = hp[0]*s[0].x + hp[1]*s[1].x + hp[2]*s[2].x + hp[3]*s[3].x;
            float ay = hp[0]*s[0].y + hp[1]*s[1].y + hp[2]*s[2].y + hp[3]*s[3].y;
            float az = hp[0]*s[0].z + hp[1]*s[1].z + hp[2]*s[2].z + hp[3]*s[3].z;
            float aw = hp[0]*s[0].w + hp[1]*s[1].w + hp[2]*s[2].w + hp[3]*s[3].w;
            v4f* op = reinterpret_cast<v4f*>(out + (b0 + r) * NCF + 4 * q);
            #pragma unroll
            for (int i = 0; i < 4; ++i) {
                v4f o;
                o.x = hrm[i][0]*s[0].x + hrm[i][1]*s[1].x + hrm[i][2]*s[2].x + hrm[i][3]*s[3].x + hq[i]*ax;
                o.y = hrm[i][0]*s[0].y + hrm[i][1]*s[1].y + hrm[i][2]*s[2].y + hrm[i][3]*s[3].y + hq[i]*ay;
                o.z = hrm[i][0]*s[0].z + hrm[i][1]*s[1].z + hrm[i][2]*s[2].z + hrm[i][3]*s[3].z + hq[i]*az;
                o.w = hrm[i][0]*s[0].w + hrm[i][1]*s[1].w + hrm[i][2]*s[2].w + hrm[i][3]*s[3].w + hq[i]*aw;
                __builtin_nontemporal_store(o, op + i * 512);
            }
        }
    }
}

extern "C" void kernel_launch(void* const* d_in, const int* in_sizes, int n_in,
                              void* d_out, int out_size, void* d_ws, size_t ws_size,
                              hipStream_t stream)
{
    const float* x        = (const float*)d_in[0];
    const float* w        = (const float*)d_in[1];
    const float* phi_pre  = (const float*)d_in[2];
    const float* phi_post = (const float*)d_in[3];
    const float* phi_res  = (const float*)d_in[4];
    const float* b_pre    = (const float*)d_in[5];
    const float* b_post   = (const float*)d_in[6];
    const float* b_res    = (const float*)d_in[7];
    const float* a_pre    = (const float*)d_in[8];
    const float* a_post   = (const float*)d_in[9];
    const float* a_res    = (const float*)d_in[10];
    float* out = (float*)d_out;
    uint16_t* phiW = (uint16_t*)d_ws;   // NJ * NCF * 2 bytes = 384 KiB

    const int B = in_sizes[0] / NCF;    // 8192

    prep_phi_kernel<<<(NJ * NCF + 255) / 256, 256, 0, stream>>>(
        w, phi_pre, phi_post, phi_res, a_pre, a_post, a_res, phiW);

    mhc_main_kernel<<<B / RPB, 1024, 0, stream>>>(
        x, phiW, b_pre, b_post, b_res, out);
}

// Round 11
// 157.462 us; speedup vs baseline: 1.2924x; 1.2924x over previous
//
#include <hip/hip_runtime.h>
#include <hip/hip_bf16.h>
#include <cstdint>

#define CH 2048
#define NCF 8192          // 4 * CH
#define NJ 24             // 4 pre + 4 post + 16 res
#define RPB 4             // batch rows per block
#define EPS_F 1e-5f
#define SINK_ITERS 20

typedef float v4f __attribute__((ext_vector_type(4)));

__device__ __forceinline__ uint32_t bf16rne(float f) {
    uint32_t u = __float_as_uint(f);
    return (u + 0x7fffu + ((u >> 16) & 1u)) >> 16;
}

// dot of 8 bf16 pairs (packed in uint4) via v_dot2_f32_bf16
__device__ __forceinline__ float dot8(const uint4& x, const uint4& p, float acc) {
    asm("v_dot2_f32_bf16 %0, %1, %2, %0" : "+v"(acc) : "v"(x.x), "v"(p.x));
    asm("v_dot2_f32_bf16 %0, %1, %2, %0" : "+v"(acc) : "v"(x.y), "v"(p.y));
    asm("v_dot2_f32_bf16 %0, %1, %2, %0" : "+v"(acc) : "v"(x.z), "v"(p.z));
    asm("v_dot2_f32_bf16 %0, %1, %2, %0" : "+v"(acc) : "v"(x.w), "v"(p.w));
    return acc;
}

// ---------------------------------------------------------------------------
// Prep: phiW[j][k] = bf16( alpha_j * w[k % CH] * phi_j[k] ),  j in [0,24)
// ---------------------------------------------------------------------------
__global__ void __launch_bounds__(256) prep_phi_kernel(
    const float* __restrict__ w,
    const float* __restrict__ phi_pre,
    const float* __restrict__ phi_post,
    const float* __restrict__ phi_res,
    const float* __restrict__ alpha_pre,
    const float* __restrict__ alpha_post,
    const float* __restrict__ alpha_res,
    uint16_t* __restrict__ phiW)
{
    int idx = blockIdx.x * 256 + threadIdx.x;
    if (idx >= NJ * NCF) return;
    int j = idx / NCF;
    int k = idx - j * NCF;
    int c = k & (CH - 1);
    float v, a;
    if (j < 4)      { v = phi_pre[j * NCF + k];        a = alpha_pre[0]; }
    else if (j < 8) { v = phi_post[(j - 4) * NCF + k]; a = alpha_post[0]; }
    else            { v = phi_res[(j - 8) * NCF + k];  a = alpha_res[0]; }
    phiW[idx] = (uint16_t)bf16rne(v * a * w[c]);
}

// ---------------------------------------------------------------------------
// Main fused kernel: 512 threads (8 waves), FOUR batch rows per block.
// LDS holds raw bf16 x for 4 rows (64 KiB). RMS scale folded into the dot
// accumulation at stream-segment boundaries. Phase B: fully-unrolled 16-step
// loop with DEPTH-2 phi prefetch (3 rotating buffers) + depth-1 LDS x.
// Sinkhorn: all waves redundant, result stored via LDS (MS), no shuffles in
// the epilogue. 2 barriers total.
// ---------------------------------------------------------------------------
__global__ void __launch_bounds__(512) mhc_main_kernel(
    const float* __restrict__ x,
    const uint16_t* __restrict__ phiW,
    const float* __restrict__ b_pre,
    const float* __restrict__ b_post,
    const float* __restrict__ b_res,
    float* __restrict__ out)
{
    const int t = threadIdx.x;
    const int lane = t & 63;
    const int wave = t >> 6;              // 0..7
    const long b0 = (long)blockIdx.x * RPB;

    __shared__ uint32_t xn[RPB][NCF / 2]; // raw bf16 x, 4 rows, 64 KiB
    __shared__ float4 red[RPB][8];
    __shared__ float H[RPB][24];          // hp(0..3) hq(4..7) logits(8..23)
    __shared__ float MS[RPB][16];         // sinkhorn output (separate: no race)

    // ---- Phase A: global -> LDS (raw bf16), sum-of-squares per stream ----
    {
        const float4* xp = reinterpret_cast<const float4*>(x + b0 * NCF);
        #pragma unroll
        for (int r = 0; r < RPB; ++r) {
            float ss0, ss1, ss2, ss3;
            {
                float4 a0 = xp[r * 2048 + t];
                float4 a1 = xp[r * 2048 + t + 512];
                float4 a2 = xp[r * 2048 + t + 1024];
                float4 a3 = xp[r * 2048 + t + 1536];
                ss0 = a0.x*a0.x + a0.y*a0.y + a0.z*a0.z + a0.w*a0.w;
                ss1 = a1.x*a1.x + a1.y*a1.y + a1.z*a1.z + a1.w*a1.w;
                ss2 = a2.x*a2.x + a2.y*a2.y + a2.z*a2.z + a2.w*a2.w;
                ss3 = a3.x*a3.x + a3.y*a3.y + a3.z*a3.z + a3.w*a3.w;
                *reinterpret_cast<uint2*>(&xn[r][2*t]) =
                    make_uint2(bf16rne(a0.x) | (bf16rne(a0.y) << 16),
                               bf16rne(a0.z) | (bf16rne(a0.w) << 16));
                *reinterpret_cast<uint2*>(&xn[r][2*t + 1024]) =
                    make_uint2(bf16rne(a1.x) | (bf16rne(a1.y) << 16),
                               bf16rne(a1.z) | (bf16rne(a1.w) << 16));
                *reinterpret_cast<uint2*>(&xn[r][2*t + 2048]) =
                    make_uint2(bf16rne(a2.x) | (bf16rne(a2.y) << 16),
                               bf16rne(a2.z) | (bf16rne(a2.w) << 16));
                *reinterpret_cast<uint2*>(&xn[r][2*t + 3072]) =
                    make_uint2(bf16rne(a3.x) | (bf16rne(a3.y) << 16),
                               bf16rne(a3.z) | (bf16rne(a3.w) << 16));
            }
            #pragma unroll
            for (int m = 1; m < 64; m <<= 1) {
                ss0 += __shfl_xor(ss0, m, 64);
                ss1 += __shfl_xor(ss1, m, 64);
                ss2 += __shfl_xor(ss2, m, 64);
                ss3 += __shfl_xor(ss3, m, 64);
            }
            if (lane == 0) red[r][wave] = make_float4(ss0, ss1, ss2, ss3);
        }
    }
    __syncthreads();

    // ---- SCL computed redundantly per thread (broadcast LDS reads) ----
    float scl[RPB][4];
    #pragma unroll
    for (int r = 0; r < RPB; ++r) {
        float sx = 0.f, sy = 0.f, sz = 0.f, sw = 0.f;
        #pragma unroll
        for (int w8 = 0; w8 < 8; ++w8) {
            float4 v = red[r][w8];
            sx += v.x; sy += v.y; sz += v.z; sw += v.w;
        }
        scl[r][0] = rsqrtf(sx * (1.0f / CH) + EPS_F);
        scl[r][1] = rsqrtf(sy * (1.0f / CH) + EPS_F);
        scl[r][2] = rsqrtf(sz * (1.0f / CH) + EPS_F);
        scl[r][3] = rsqrtf(sw * (1.0f / CH) + EPS_F);
    }

    // ---- Phase B: wave w dots 4 raw rows against phi rows 3w..3w+2 ----
    // 16 fully-unrolled steps; depth-2 phi prefetch, depth-1 x prefetch.
    float accT[3][RPB] = {};
    float accS[3][RPB] = {};
    {
        const uint16_t* pw = phiW + (size_t)(wave * 3) * NCF;
        const int kl = 8 * lane;
        const uint4* xr0 = reinterpret_cast<const uint4*>(xn[0]);
        const uint4* xr1 = reinterpret_cast<const uint4*>(xn[1]);
        const uint4* xr2 = reinterpret_cast<const uint4*>(xn[2]);
        const uint4* xr3 = reinterpret_cast<const uint4*>(xn[3]);

        uint4 pbuf[3][3];                  // [step % 3][j-row]
        uint4 xbuf[2][4];                  // [step & 1][batch row]

        #pragma unroll
        for (int jl = 0; jl < 3; ++jl) {
            pbuf[0][jl] = *reinterpret_cast<const uint4*>(pw + jl * NCF + kl);
            pbuf[1][jl] = *reinterpret_cast<const uint4*>(pw + jl * NCF + 512 + kl);
        }
        xbuf[0][0] = xr0[lane]; xbuf[0][1] = xr1[lane];
        xbuf[0][2] = xr2[lane]; xbuf[0][3] = xr3[lane];

        #pragma unroll
        for (int u = 0; u < 16; ++u) {
            const int cur = u % 3;
            const int nxt = (u + 2) % 3;
            const int xc = u & 1;
            const int xq = (u + 1) & 1;
            if (u + 1 < 16) {              // prefetch x step u+1 (LDS)
                const int i1 = 64 * (u + 1) + lane;
                xbuf[xq][0] = xr0[i1]; xbuf[xq][1] = xr1[i1];
                xbuf[xq][2] = xr2[i1]; xbuf[xq][3] = xr3[i1];
            }
            if (u + 2 < 16) {              // prefetch phi step u+2 (L2)
                const int k2 = 512 * (u + 2) + kl;
                #pragma unroll
                for (int jl = 0; jl < 3; ++jl)
                    pbuf[nxt][jl] = *reinterpret_cast<const uint4*>(pw + jl * NCF + k2);
            }
            #pragma unroll
            for (int jl = 0; jl < 3; ++jl) {
                accS[jl][0] = dot8(xbuf[xc][0], pbuf[cur][jl], accS[jl][0]);
                accS[jl][1] = dot8(xbuf[xc][1], pbuf[cur][jl], accS[jl][1]);
                accS[jl][2] = dot8(xbuf[xc][2], pbuf[cur][jl], accS[jl][2]);
                accS[jl][3] = dot8(xbuf[xc][3], pbuf[cur][jl], accS[jl][3]);
            }
            if ((u & 3) == 3) {            // end of stream segment: fold scl
                const int s = u >> 2;
                #pragma unroll
                for (int jl = 0; jl < 3; ++jl) {
                    #pragma unroll
                    for (int r = 0; r < RPB; ++r) {
                        accT[jl][r] = fmaf(scl[r][s], accS[jl][r], accT[jl][r]);
                        accS[jl][r] = 0.f;
                    }
                }
            }
        }
    }
    {
        #pragma unroll
        for (int m = 1; m < 64; m <<= 1) {
            #pragma unroll
            for (int jl = 0; jl < 3; ++jl) {
                #pragma unroll
                for (int r = 0; r < RPB; ++r)
                    accT[jl][r] += __shfl_xor(accT[jl][r], m, 64);
            }
        }
        if (lane == 0) {                 // fold bias, write H directly
            #pragma unroll
            for (int jl = 0; jl < 3; ++jl) {
                int j = 3 * wave + jl;
                float bias;
                if (j < 4)      bias = b_pre[j];
                else if (j < 8) bias = b_post[j - 4];
                else            bias = b_res[j - 8];
                #pragma unroll
                for (int r = 0; r < RPB; ++r) H[r][j] = accT[jl][r] + bias;
            }
        }
    }
    __syncthreads();

    // ---- Sinkhorn: every wave computes all 4 rows redundantly (16-lane
    // groups); result goes to MS (identical-value write race is benign).
    {
        const int r = lane >> 4;
        const int q = lane & 15;          // q = i*4 + jx
        float L = H[r][8 + q];
        float mx = L;
        mx = fmaxf(mx, __shfl_xor(mx, 1, 64));
        mx = fmaxf(mx, __shfl_xor(mx, 2, 64));
        mx = fmaxf(mx, __shfl_xor(mx, 4, 64));
        mx = fmaxf(mx, __shfl_xor(mx, 8, 64));
        float m = __expf(L - mx);
        #pragma unroll
        for (int it = 0; it < SINK_ITERS; ++it) {
            float rs = m + __shfl_xor(m, 1, 64);
            rs += __shfl_xor(rs, 2, 64);
            m = m * __builtin_amdgcn_rcpf(rs + EPS_F);   // row normalize
            float cs = m + __shfl_xor(m, 4, 64);
            cs += __shfl_xor(cs, 8, 64);
            m = m * __builtin_amdgcn_rcpf(cs + EPS_F);   // col normalize
        }
        MS[r][q] = m;                     // own wave reads after own write
    }

    // ---- Phase D: mixing epilogue from LDS raw bf16 x; h via LDS float4 --
    #pragma unroll
    for (int r = 0; r < RPB; ++r) {
        const float4 hp = *reinterpret_cast<const float4*>(&H[r][0]);
        const float4 hq = *reinterpret_cast<const float4*>(&H[r][4]);
        float4 hrm[4];
        #pragma unroll
        for (int i = 0; i < 4; ++i)
            hrm[i] = *reinterpret_cast<const float4*>(&MS[r][4 * i]);
        float4 s[4];
        #pragma unroll
        for (int jj = 0; jj < 4; ++jj) {
            uint2 pk = *reinterpret_cast<const uint2*>(&xn[r][2 * t + 1024 * jj]);
            s[jj].x = __uint_as_float(pk.x << 16);
            s[jj].y = __uint_as_float(pk.x & 0xffff0000u);
            s[jj].z = __uint_as_float(pk.y << 16);
            s[jj].w = __uint_as_float(pk.y & 0xffff0000u);
        }
        float ax = hp.x*s[0].x + hp.y*s[1].x + hp.z*s[2].x + hp.w*s[3].x;
        float ay = hp.x*s[0].y + hp.y*s[1].y + hp.z*s[2].y + hp.w*s[3].y;
        float az = hp.x*s[0].z + hp.y*s[1].z + hp.z*s[2].z + hp.w*s[3].z;
        float aw = hp.x*s[0].w + hp.y*s[1].w + hp.z*s[2].w + hp.w*s[3].w;
        const float hqv[4] = {hq.x, hq.y, hq.z, hq.w};
        v4f* op = reinterpret_cast<v4f*>(out + (b0 + r) * NCF + 4 * t);
        #pragma unroll
        for (int i = 0; i < 4; ++i) {
            v4f o;
            o.x = hrm[i].x*s[0].x + hrm[i].y*s[1].x + hrm[i].z*s[2].x + hrm[i].w*s[3].x + hqv[i]*ax;
            o.y = hrm[i].x*s[0].y + hrm[i].y*s[1].y + hrm[i].z*s[2].y + hrm[i].w*s[3].y + hqv[i]*ay;
            o.z = hrm[i].x*s[0].z + hrm[i].y*s[1].z + hrm[i].z*s[2].z + hrm[i].w*s[3].z + hqv[i]*az;
            o.w = hrm[i].x*s[0].w + hrm[i].y*s[1].w + hrm[i].z*s[2].w + hrm[i].w*s[3].w + hqv[i]*aw;
            __builtin_nontemporal_store(o, op + i * 512);
        }
    }
}

extern "C" void kernel_launch(void* const* d_in, const int* in_sizes, int n_in,
                              void* d_out, int out_size, void* d_ws, size_t ws_size,
                              hipStream_t stream)
{
    const float* x        = (const float*)d_in[0];
    const float* w        = (const float*)d_in[1];
    const float* phi_pre  = (const float*)d_in[2];
    const float* phi_post = (const float*)d_in[3];
    const float* phi_res  = (const float*)d_in[4];
    const float* b_pre    = (const float*)d_in[5];
    const float* b_post   = (const float*)d_in[6];
    const float* b_res    = (const float*)d_in[7];
    const float* a_pre    = (const float*)d_in[8];
    const float* a_post   = (const float*)d_in[9];
    const float* a_res    = (const float*)d_in[10];
    float* out = (float*)d_out;
    uint16_t* phiW = (uint16_t*)d_ws;   // NJ * NCF * 2 bytes = 384 KiB

    const int B = in_sizes[0] / NCF;    // 8192

    prep_phi_kernel<<<(NJ * NCF + 255) / 256, 256, 0, stream>>>(
        w, phi_pre, phi_post, phi_res, a_pre, a_post, a_res, phiW);

    mhc_main_kernel<<<B / RPB, 512, 0, stream>>>(
        x, phiW, b_pre, b_post, b_res, out);
}

// Round 12
// 133.133 us; speedup vs baseline: 1.5285x; 1.1827x over previous
//
#include <hip/hip_runtime.h>
#include <hip/hip_bf16.h>
#include <cstdint>

#define CH 2048
#define NCF 8192          // 4 * CH
#define NJ 24             // 4 pre + 4 post + 16 res
#define RPB 4             // batch rows per block
#define EPS_F 1e-5f
#define SINK_ITERS 20

typedef float v4f __attribute__((ext_vector_type(4)));

__device__ __forceinline__ uint32_t bf16rne(float f) {
    uint32_t u = __float_as_uint(f);
    return (u + 0x7fffu + ((u >> 16) & 1u)) >> 16;
}

// dot of 8 bf16 pairs (packed in uint4) via v_dot2_f32_bf16
__device__ __forceinline__ float dot8(const uint4& x, const uint4& p, float acc) {
    asm("v_dot2_f32_bf16 %0, %1, %2, %0" : "+v"(acc) : "v"(x.x), "v"(p.x));
    asm("v_dot2_f32_bf16 %0, %1, %2, %0" : "+v"(acc) : "v"(x.y), "v"(p.y));
    asm("v_dot2_f32_bf16 %0, %1, %2, %0" : "+v"(acc) : "v"(x.z), "v"(p.z));
    asm("v_dot2_f32_bf16 %0, %1, %2, %0" : "+v"(acc) : "v"(x.w), "v"(p.w));
    return acc;
}

// ---------------------------------------------------------------------------
// Prep: phiW[j][k] = bf16( alpha_j * w[k % CH] * phi_j[k] ),  j in [0,24)
// ---------------------------------------------------------------------------
__global__ void __launch_bounds__(256) prep_phi_kernel(
    const float* __restrict__ w,
    const float* __restrict__ phi_pre,
    const float* __restrict__ phi_post,
    const float* __restrict__ phi_res,
    const float* __restrict__ alpha_pre,
    const float* __restrict__ alpha_post,
    const float* __restrict__ alpha_res,
    uint16_t* __restrict__ phiW)
{
    int idx = blockIdx.x * 256 + threadIdx.x;
    if (idx >= NJ * NCF) return;
    int j = idx / NCF;
    int k = idx - j * NCF;
    int c = k & (CH - 1);
    float v, a;
    if (j < 4)      { v = phi_pre[j * NCF + k];        a = alpha_pre[0]; }
    else if (j < 8) { v = phi_post[(j - 4) * NCF + k]; a = alpha_post[0]; }
    else            { v = phi_res[(j - 8) * NCF + k];  a = alpha_res[0]; }
    phiW[idx] = (uint16_t)bf16rne(v * a * w[c]);
}

// ---------------------------------------------------------------------------
// Main fused kernel: 512 threads (8 waves), FOUR batch rows per block.
// LDS holds raw bf16 x for 4 rows (64 KiB). RMS scale folded into the dot
// accumulation at stream-segment boundaries. Phase B: R9's 2-step ping-pong
// phi prefetch. Sinkhorn: all waves redundant, result broadcast via MS LDS
// (no shuffles in the epilogue). 2 barriers total.
// ---------------------------------------------------------------------------
__global__ void __launch_bounds__(512) mhc_main_kernel(
    const float* __restrict__ x,
    const uint16_t* __restrict__ phiW,
    const float* __restrict__ b_pre,
    const float* __restrict__ b_post,
    const float* __restrict__ b_res,
    float* __restrict__ out)
{
    const int t = threadIdx.x;
    const int lane = t & 63;
    const int wave = t >> 6;              // 0..7
    const long b0 = (long)blockIdx.x * RPB;

    __shared__ uint32_t xn[RPB][NCF / 2]; // raw bf16 x, 4 rows, 64 KiB
    __shared__ float4 red[RPB][8];
    __shared__ float H[RPB][24] __attribute__((aligned(16)));
    __shared__ float MS[RPB][16] __attribute__((aligned(16)));

    // ---- Phase A: global -> LDS (raw bf16), sum-of-squares per stream ----
    // 2 rows batched: 8 float4 loads in flight before processing.
    {
        const float4* xp = reinterpret_cast<const float4*>(x + b0 * NCF);
        #pragma unroll
        for (int rp = 0; rp < RPB; rp += 2) {
            float4 a[2][4];
            #pragma unroll
            for (int rr = 0; rr < 2; ++rr)
                #pragma unroll
                for (int jj = 0; jj < 4; ++jj)
                    a[rr][jj] = xp[(rp + rr) * 2048 + t + 512 * jj];

            float ss[2][4];
            #pragma unroll
            for (int rr = 0; rr < 2; ++rr) {
                const int r = rp + rr;
                #pragma unroll
                for (int jj = 0; jj < 4; ++jj) {
                    float4 v = a[rr][jj];
                    ss[rr][jj] = v.x*v.x + v.y*v.y + v.z*v.z + v.w*v.w;
                    *reinterpret_cast<uint2*>(&xn[r][2*t + 1024*jj]) =
                        make_uint2(bf16rne(v.x) | (bf16rne(v.y) << 16),
                                   bf16rne(v.z) | (bf16rne(v.w) << 16));
                }
            }
            #pragma unroll
            for (int m = 1; m < 64; m <<= 1) {
                #pragma unroll
                for (int rr = 0; rr < 2; ++rr)
                    #pragma unroll
                    for (int jj = 0; jj < 4; ++jj)
                        ss[rr][jj] += __shfl_xor(ss[rr][jj], m, 64);
            }
            if (lane == 0) {
                red[rp][wave]     = make_float4(ss[0][0], ss[0][1], ss[0][2], ss[0][3]);
                red[rp + 1][wave] = make_float4(ss[1][0], ss[1][1], ss[1][2], ss[1][3]);
            }
        }
    }
    __syncthreads();

    // ---- SCL computed redundantly per thread (broadcast LDS reads) ----
    float scl[RPB][4];
    #pragma unroll
    for (int r = 0; r < RPB; ++r) {
        float sx = 0.f, sy = 0.f, sz = 0.f, sw = 0.f;
        #pragma unroll
        for (int w8 = 0; w8 < 8; ++w8) {
            float4 v = red[r][w8];
            sx += v.x; sy += v.y; sz += v.z; sw += v.w;
        }
        scl[r][0] = rsqrtf(sx * (1.0f / CH) + EPS_F);
        scl[r][1] = rsqrtf(sy * (1.0f / CH) + EPS_F);
        scl[r][2] = rsqrtf(sz * (1.0f / CH) + EPS_F);
        scl[r][3] = rsqrtf(sw * (1.0f / CH) + EPS_F);
    }

    // ---- Phase B: wave w dots 4 raw rows against phi rows 3w..3w+2 ----
    // 16 steps of 512 elems; 2-step ping-pong; scl folded per stream segment.
    float accT[3][RPB] = {};
    float accS[3][RPB] = {};
    {
        const uint16_t* pw = phiW + (size_t)(wave * 3) * NCF;
        const int kl = 8 * lane;
        const uint4* xr0 = reinterpret_cast<const uint4*>(xn[0]);
        const uint4* xr1 = reinterpret_cast<const uint4*>(xn[1]);
        const uint4* xr2 = reinterpret_cast<const uint4*>(xn[2]);
        const uint4* xr3 = reinterpret_cast<const uint4*>(xn[3]);

        uint4 pA0 = *reinterpret_cast<const uint4*>(pw + 0 * NCF + kl);
        uint4 pA1 = *reinterpret_cast<const uint4*>(pw + 1 * NCF + kl);
        uint4 pA2 = *reinterpret_cast<const uint4*>(pw + 2 * NCF + kl);
        uint4 xA0 = xr0[lane], xA1 = xr1[lane], xA2 = xr2[lane], xA3 = xr3[lane];

        #pragma unroll
        for (int u = 0; u < 16; u += 2) {
            const int iB = 64 * (u + 1) + lane;
            const int kB = 512 * (u + 1) + kl;
            uint4 pB0 = *reinterpret_cast<const uint4*>(pw + 0 * NCF + kB);
            uint4 pB1 = *reinterpret_cast<const uint4*>(pw + 1 * NCF + kB);
            uint4 pB2 = *reinterpret_cast<const uint4*>(pw + 2 * NCF + kB);
            uint4 xB0 = xr0[iB], xB1 = xr1[iB], xB2 = xr2[iB], xB3 = xr3[iB];

            accS[0][0] = dot8(xA0, pA0, accS[0][0]);
            accS[0][1] = dot8(xA1, pA0, accS[0][1]);
            accS[0][2] = dot8(xA2, pA0, accS[0][2]);
            accS[0][3] = dot8(xA3, pA0, accS[0][3]);
            accS[1][0] = dot8(xA0, pA1, accS[1][0]);
            accS[1][1] = dot8(xA1, pA1, accS[1][1]);
            accS[1][2] = dot8(xA2, pA1, accS[1][2]);
            accS[1][3] = dot8(xA3, pA1, accS[1][3]);
            accS[2][0] = dot8(xA0, pA2, accS[2][0]);
            accS[2][1] = dot8(xA1, pA2, accS[2][1]);
            accS[2][2] = dot8(xA2, pA2, accS[2][2]);
            accS[2][3] = dot8(xA3, pA2, accS[2][3]);

            if (u + 2 < 16) {
                const int iA = 64 * (u + 2) + lane;
                const int kA = 512 * (u + 2) + kl;
                pA0 = *reinterpret_cast<const uint4*>(pw + 0 * NCF + kA);
                pA1 = *reinterpret_cast<const uint4*>(pw + 1 * NCF + kA);
                pA2 = *reinterpret_cast<const uint4*>(pw + 2 * NCF + kA);
                xA0 = xr0[iA]; xA1 = xr1[iA]; xA2 = xr2[iA]; xA3 = xr3[iA];
            }

            accS[0][0] = dot8(xB0, pB0, accS[0][0]);
            accS[0][1] = dot8(xB1, pB0, accS[0][1]);
            accS[0][2] = dot8(xB2, pB0, accS[0][2]);
            accS[0][3] = dot8(xB3, pB0, accS[0][3]);
            accS[1][0] = dot8(xB0, pB1, accS[1][0]);
            accS[1][1] = dot8(xB1, pB1, accS[1][1]);
            accS[1][2] = dot8(xB2, pB1, accS[1][2]);
            accS[1][3] = dot8(xB3, pB1, accS[1][3]);
            accS[2][0] = dot8(xB0, pB2, accS[2][0]);
            accS[2][1] = dot8(xB1, pB2, accS[2][1]);
            accS[2][2] = dot8(xB2, pB2, accS[2][2]);
            accS[2][3] = dot8(xB3, pB2, accS[2][3]);

            if (((u + 1) & 3) == 3) {               // end of stream segment
                const int s = (u + 1) >> 2;
                #pragma unroll
                for (int jl = 0; jl < 3; ++jl) {
                    #pragma unroll
                    for (int r = 0; r < RPB; ++r) {
                        accT[jl][r] = fmaf(scl[r][s], accS[jl][r], accT[jl][r]);
                        accS[jl][r] = 0.f;
                    }
                }
            }
        }
    }
    {
        #pragma unroll
        for (int m = 1; m < 64; m <<= 1) {
            #pragma unroll
            for (int jl = 0; jl < 3; ++jl) {
                #pragma unroll
                for (int r = 0; r < RPB; ++r)
                    accT[jl][r] += __shfl_xor(accT[jl][r], m, 64);
            }
        }
        if (lane == 0) {                 // fold bias, write H directly
            #pragma unroll
            for (int jl = 0; jl < 3; ++jl) {
                int j = 3 * wave + jl;
                float bias;
                if (j < 4)      bias = b_pre[j];
                else if (j < 8) bias = b_post[j - 4];
                else            bias = b_res[j - 8];
                #pragma unroll
                for (int r = 0; r < RPB; ++r) H[r][j] = accT[jl][r] + bias;
            }
        }
    }
    __syncthreads();

    // ---- Sinkhorn: every wave computes all 4 rows redundantly (16-lane
    // groups); identical-value writes to MS (benign race, own-wave read).
    {
        const int r = lane >> 4;
        const int q = lane & 15;          // q = i*4 + jx
        float L = H[r][8 + q];
        float mx = L;
        mx = fmaxf(mx, __shfl_xor(mx, 1, 64));
        mx = fmaxf(mx, __shfl_xor(mx, 2, 64));
        mx = fmaxf(mx, __shfl_xor(mx, 4, 64));
        mx = fmaxf(mx, __shfl_xor(mx, 8, 64));
        float m = __expf(L - mx);
        #pragma unroll
        for (int it = 0; it < SINK_ITERS; ++it) {
            float rs = m + __shfl_xor(m, 1, 64);
            rs += __shfl_xor(rs, 2, 64);
            m = m * __builtin_amdgcn_rcpf(rs + EPS_F);   // row normalize
            float cs = m + __shfl_xor(m, 4, 64);
            cs += __shfl_xor(cs, 8, 64);
            m = m * __builtin_amdgcn_rcpf(cs + EPS_F);   // col normalize
        }
        MS[r][q] = m;
    }

    // ---- Phase D: mixing epilogue from LDS raw bf16 x; h via LDS float4 --
    #pragma unroll
    for (int r = 0; r < RPB; ++r) {
        const float4 hp = *reinterpret_cast<const float4*>(&H[r][0]);
        const float4 hq = *reinterpret_cast<const float4*>(&H[r][4]);
        float4 hrm[4];
        #pragma unroll
        for (int i = 0; i < 4; ++i)
            hrm[i] = *reinterpret_cast<const float4*>(&MS[r][4 * i]);
        float4 s[4];
        #pragma unroll
        for (int jj = 0; jj < 4; ++jj) {
            uint2 pk = *reinterpret_cast<const uint2*>(&xn[r][2 * t + 1024 * jj]);
            s[jj].x = __uint_as_float(pk.x << 16);
            s[jj].y = __uint_as_float(pk.x & 0xffff0000u);
            s[jj].z = __uint_as_float(pk.y << 16);
            s[jj].w = __uint_as_float(pk.y & 0xffff0000u);
        }
        float ax = hp.x*s[0].x + hp.y*s[1].x + hp.z*s[2].x + hp.w*s[3].x;
        float ay = hp.x*s[0].y + hp.y*s[1].y + hp.z*s[2].y + hp.w*s[3].y;
        float az = hp.x*s[0].z + hp.y*s[1].z + hp.z*s[2].z + hp.w*s[3].z;
        float aw = hp.x*s[0].w + hp.y*s[1].w + hp.z*s[2].w + hp.w*s[3].w;
        const float hqv[4] = {hq.x, hq.y, hq.z, hq.w};
        v4f* op = reinterpret_cast<v4f*>(out + (b0 + r) * NCF + 4 * t);
        #pragma unroll
        for (int i = 0; i < 4; ++i) {
            v4f o;
            o.x = hrm[i].x*s[0].x + hrm[i].y*s[1].x + hrm[i].z*s[2].x + hrm[i].w*s[3].x + hqv[i]*ax;
            o.y = hrm[i].x*s[0].y + hrm[i].y*s[1].y + hrm[i].z*s[2].y + hrm[i].w*s[3].y + hqv[i]*ay;
            o.z = hrm[i].x*s[0].z + hrm[i].y*s[1].z + hrm[i].z*s[2].z + hrm[i].w*s[3].z + hqv[i]*az;
            o.w = hrm[i].x*s[0].w + hrm[i].y*s[1].w + hrm[i].z*s[2].w + hrm[i].w*s[3].w + hqv[i]*aw;
            __builtin_nontemporal_store(o, op + i * 512);
        }
    }
}

extern "C" void kernel_launch(void* const* d_in, const int* in_sizes, int n_in,
                              void* d_out, int out_size, void* d_ws, size_t ws_size,
                              hipStream_t stream)
{
    const float* x        = (const float*)d_in[0];
    const float* w        = (const float*)d_in[1];
    const float* phi_pre  = (const float*)d_in[2];
    const float* phi_post = (const float*)d_in[3];
    const float* phi_res  = (const float*)d_in[4];
    const float* b_pre    = (const float*)d_in[5];
    const float* b_post   = (const float*)d_in[6];
    const float* b_res    = (const float*)d_in[7];
    const float* a_pre    = (const float*)d_in[8];
    const float* a_post   = (const float*)d_in[9];
    const float* a_res    = (const float*)d_in[10];
    float* out = (float*)d_out;
    uint16_t* phiW = (uint16_t*)d_ws;   // NJ * NCF * 2 bytes = 384 KiB

    const int B = in_sizes[0] / NCF;    // 8192

    prep_phi_kernel<<<(NJ * NCF + 255) / 256, 256, 0, stream>>>(
        w, phi_pre, phi_post, phi_res, a_pre, a_post, a_res, phiW);

    mhc_main_kernel<<<B / RPB, 512, 0, stream>>>(
        x, phiW, b_pre, b_post, b_res, out);
}